// Round 9
// baseline (434.513 us; speedup 1.0000x reference)
//
#include <hip/hip_runtime.h>

#define B 256
#define KDIM 8
#define IDIM 1152
#define CDIM 10
#define CO 160
#define IK 9216        // IDIM*KDIM
#define NBLK 256

typedef __bf16 bf16x8 __attribute__((ext_vector_type(8)));
typedef unsigned short ushort8 __attribute__((ext_vector_type(8)));
typedef float f32x4 __attribute__((ext_vector_type(4)));

__device__ __forceinline__ unsigned short f2bf(float f) {
  unsigned u = __float_as_uint(f);
  unsigned r = u + 0x7fff + ((u >> 16) & 1);   // RNE
  return (unsigned short)(r >> 16);
}

union U8B8 { ushort8 u; bf16x8 h; };

// Grid-wide barrier: monotonic epoch counter, device-scope.
// All 256 blocks are co-resident (41KB LDS -> 3 blocks/CU capacity, grid=256
// on 256 CUs), so spinning is safe. Polls are agent-scope atomic loads (bypass
// the non-coherent per-XCD L2s); fences publish/acquire plain stores.
__device__ __forceinline__ void gbar(int* cnt, int& ep) {
  __syncthreads();
  ep += NBLK;
  if (threadIdx.x == 0) {
    __threadfence();                       // release prior writes
    atomicAdd(cnt, 1);
    int guard = 0;
    while (__hip_atomic_load(cnt, __ATOMIC_RELAXED, __HIP_MEMORY_SCOPE_AGENT) < ep) {
      __builtin_amdgcn_s_sleep(8);
      if (++guard > 30000000) break;       // deadlock bailout -> wrong answer, not hang
    }
  }
  __syncthreads();
  __threadfence();                         // acquire: invalidate stale L1/L2
}

// ---------------------------------------------------------------------------
// Single persistent kernel, 256 blocks x 256 threads, plain launch.
// Phases (separated by gbar):
//  P: x -> xtbT/xtkb bf16; W -> Wq=bf16(W/1152); zero logits
//  iter 0..2:  S (MFMA split-K s-GEMM, NP partials)
//              SQ (reduce+squash -> outT bf16 / final f32 out)
//              [it<2] AGR (MFMA y-GEMM + W-contract -> atomic logits)
//              [it<2] Q  (softmax + Wq = bf16(W*q))
// ---------------------------------------------------------------------------
template <int NP>
__global__ void __launch_bounds__(256)
caps_all(const float* __restrict__ x, const float* __restrict__ W,
         float* __restrict__ out, int* __restrict__ bar,
         float* __restrict__ logits, float* __restrict__ s_part,
         unsigned short* __restrict__ xtbT, unsigned short* __restrict__ xtkb,
         unsigned short* __restrict__ Wq, unsigned short* __restrict__ outT) {
  __shared__ __align__(16) unsigned char smem[41280];
  const int gid = blockIdx.x;
  const int t = threadIdx.x;
  const int w4 = t >> 6, l = t & 63;
  const int lr = l & 15, lq = l >> 4;
  const int gwid = gid * 4 + w4;           // global wave id 0..1023
  int ep = 0;

  // ================= Phase P: prep =================
  for (int job = gid; job < 360; job += NBLK) {
    if (job < 288) {
      float* tf = (float*)smem;            // tile[k][bb][ii]: k*1056+bb*33+ii
      const int i0 = (job % 36) * 32;
      const int b0 = (job / 36) * 32;
      const int tx = t & 31, ty = t >> 5;
#pragma unroll
      for (int r = 0; r < 4; ++r) {
        int b = b0 + ty + r * 8;
#pragma unroll
        for (int k = 0; k < 8; ++k)
          tf[k * 1056 + (ty + r * 8) * 33 + tx] =
              x[((size_t)b * KDIM + k) * IDIM + i0 + tx];
      }
      __syncthreads();
      // xtbT[b][i*8+k]
#pragma unroll
      for (int r = 0; r < 4; ++r) {
        int idx = r * 256 + t;
        int bb = idx >> 5, ii = idx & 31;
        ushort8 v;
#pragma unroll
        for (int k = 0; k < 8; ++k) v[k] = f2bf(tf[k * 1056 + bb * 33 + ii]);
        *reinterpret_cast<ushort8*>(&xtbT[(size_t)(b0 + bb) * IK + (i0 + ii) * 8]) = v;
      }
      // xtkb[(i*8+k)][b]
#pragma unroll
      for (int ii = 0; ii < 32; ++ii)
        xtkb[((size_t)(i0 + ii) * 8 + ty) * B + b0 + tx] =
            f2bf(tf[ty * 1056 + tx * 33 + ii]);
    } else {
      unsigned short* wt = (unsigned short*)smem;  // wt[ii][j], stride 1288
      const int bz = job - 288;                    // 0..71
      const int i0 = bz * 16;
      const float sc = 1.f / (float)IDIM;
#pragma unroll
      for (int ii = 0; ii < 16; ++ii) {
        const float* src = &W[(size_t)(i0 + ii) * 1280];
#pragma unroll
        for (int p = 0; p < 5; ++p) {
          int j = p * 256 + t;
          wt[ii * 1288 + j] = f2bf(src[j] * sc);
        }
      }
      __syncthreads();
#pragma unroll
      for (int p = 0; p < 10; ++p) {
        int idx = p * 256 + t;
        int co = idx >> 4, ii = idx & 15;
        ushort8 v = *reinterpret_cast<const ushort8*>(&wt[ii * 1288 + co * 8]);
        *reinterpret_cast<ushort8*>(&Wq[(size_t)co * IK + (i0 + ii) * 8]) = v;
      }
    }
    __syncthreads();
  }
  if (gid < 45) logits[gid * 256 + t] = 0.f;
  gbar(bar, ep);

  for (int it = 0; it < 3; ++it) {
    // ================= Phase S: split-K MFMA s-GEMM =================
    {
      constexpr int KSPAN = IK / NP;       // K-elements per split
      constexpr int CHUNKS = KSPAN / 32;
      for (int job = gwid; job < 160 * NP; job += 1024) {
        const int bt = job & 15;
        const int cc = (job >> 4) % 10;
        const int g = job / 160;
        const unsigned short* Ap = &Wq[(size_t)(cc * 16 + lr) * IK + g * KSPAN + lq * 8];
        const unsigned short* Bp = &xtbT[(size_t)(bt * 16 + lr) * IK + g * KSPAN + lq * 8];
        f32x4 acc = (f32x4){0.f, 0.f, 0.f, 0.f};
#pragma unroll 3
        for (int t9 = 0; t9 < CHUNKS; ++t9) {
          U8B8 a;  a.u  = *reinterpret_cast<const ushort8*>(Ap + t9 * 32);
          U8B8 bb; bb.u = *reinterpret_cast<const ushort8*>(Bp + t9 * 32);
          acc = __builtin_amdgcn_mfma_f32_16x16x32_bf16(a.h, bb.h, acc, 0, 0, 0);
        }
        *reinterpret_cast<f32x4*>(
            &s_part[((size_t)g * B + bt * 16 + lr) * CO + cc * 16 + lq * 4]) = acc;
      }
    }
    gbar(bar, ep);

    // ================= Phase SQ: reduce partials + squash =================
    {
      float* sq = (float*)smem;      // [160] v^2
      float* fo = sq + 160;          // [16] scale per o
      const int b = gid;
      float vv = 0.f;
      if (t < CO) {
#pragma unroll 4
        for (int g = 0; g < NP; ++g)
          vv += s_part[((size_t)g * B + b) * CO + t];
        sq[t] = vv * vv;
      }
      __syncthreads();
      if (t < 16) {
        float ns = 0.f;
#pragma unroll
        for (int c = 0; c < CDIM; ++c) ns += sq[c * 16 + t];
        fo[t] = (ns / (1.f + ns)) / (sqrtf(ns) + 1e-10f);
      }
      __syncthreads();
      if (t < CO) {
        float r = vv * fo[t & 15];
        if (it == 2) out[(size_t)b * CO + t] = r;
        else         outT[(size_t)t * B + b] = f2bf(r);
      }
    }
    if (it == 2) break;
    gbar(bar, ep);

    // ================= Phase AGR: MFMA y-GEMM + W-contract =================
    {
      float* yl = (float*)smem;      // [64][161]
      for (int job = gid; job < 576; job += NBLK) {
        const int bx = job % 144, bh = job / 144;
        __syncthreads();             // protect yl reuse across jobs
        f32x4 acc[10];
#pragma unroll
        for (int nt = 0; nt < 10; ++nt) acc[nt] = (f32x4){0.f, 0.f, 0.f, 0.f};
        const unsigned short* Ap =
            &xtkb[(size_t)(bx * 64 + w4 * 16 + lr) * B + bh * 64 + lq * 8];
        const unsigned short* Bp = &outT[(size_t)lr * B + bh * 64 + lq * 8];
#pragma unroll
        for (int kc = 0; kc < 2; ++kc) {
          U8B8 a; a.u = *reinterpret_cast<const ushort8*>(Ap + kc * 32);
#pragma unroll
          for (int nt = 0; nt < 10; ++nt) {
            U8B8 bv;
            bv.u = *reinterpret_cast<const ushort8*>(Bp + (size_t)nt * 16 * B + kc * 32);
            acc[nt] = __builtin_amdgcn_mfma_f32_16x16x32_bf16(a.h, bv.h, acc[nt], 0, 0, 0);
          }
        }
#pragma unroll
        for (int nt = 0; nt < 10; ++nt)
#pragma unroll
          for (int j = 0; j < 4; ++j)
            yl[(w4 * 16 + lq * 4 + j) * 161 + nt * 16 + lr] = acc[nt][j];
        __syncthreads();
        if (t < 160) {
          const int ii = t / 20, rem = t % 20, ccl = rem >> 1, oh = rem & 1;
          const float* Wp = &W[((size_t)(bx * 8 + ii) * CDIM + ccl) * 128 + oh * 64];
          float sum = 0.f;
#pragma unroll
          for (int o = 0; o < 8; ++o) {
            float4 w0 = *(const float4*)(&Wp[o * 8]);
            float4 w1 = *(const float4*)(&Wp[o * 8 + 4]);
            int co = ccl * 16 + oh * 8 + o;
            sum += w0.x * yl[(ii * 8 + 0) * 161 + co] + w0.y * yl[(ii * 8 + 1) * 161 + co]
                 + w0.z * yl[(ii * 8 + 2) * 161 + co] + w0.w * yl[(ii * 8 + 3) * 161 + co]
                 + w1.x * yl[(ii * 8 + 4) * 161 + co] + w1.y * yl[(ii * 8 + 5) * 161 + co]
                 + w1.z * yl[(ii * 8 + 6) * 161 + co] + w1.w * yl[(ii * 8 + 7) * 161 + co];
          }
          sum += __shfl_xor(sum, 1);
          if (oh == 0)
            atomicAdd(&logits[(bx * 8 + ii) * CDIM + ccl], sum * (1.f / (float)B));
        }
      }
    }
    gbar(bar, ep);

    // ================= Phase Q: softmax + Wq = bf16(W*q) =================
    if (gid < 40) {
      const int c = gid >> 2;
      const int o0 = (gid & 3) * 4;
      float* cls = (float*)smem;     // [1152]
      float* red4 = cls + IDIM;      // [4]
      float m = -1e30f;
      for (int i = t; i < IDIM; i += 256) {
        float v = logits[i * CDIM + c];
        cls[i] = v;
        m = fmaxf(m, v);
      }
#pragma unroll
      for (int off = 32; off; off >>= 1) m = fmaxf(m, __shfl_xor(m, off));
      if ((t & 63) == 0) red4[t >> 6] = m;
      __syncthreads();
      m = fmaxf(fmaxf(red4[0], red4[1]), fmaxf(red4[2], red4[3]));
      __syncthreads();
      float ps = 0.f;
      for (int i = t; i < IDIM; i += 256) {
        float e = expf(cls[i] - m);
        cls[i] = e;
        ps += e;
      }
#pragma unroll
      for (int off = 32; off; off >>= 1) ps += __shfl_xor(ps, off);
      if ((t & 63) == 0) red4[t >> 6] = ps;
      __syncthreads();
      const float rinv = 1.f / (red4[0] + red4[1] + red4[2] + red4[3]);
#pragma unroll
      for (int r = 0; r < 4; ++r) {
        int row = c * 16 + o0 + r;
        for (int i = t; i < IDIM; i += 256) {
          const float* src = &W[((size_t)i * CDIM + c) * 128 + (o0 + r) * 8];
          float q = cls[i] * rinv;
          float4 w0 = *(const float4*)src;
          float4 w1 = *(const float4*)(src + 4);
          ushort8 v;
          v[0] = f2bf(w0.x * q); v[1] = f2bf(w0.y * q);
          v[2] = f2bf(w0.z * q); v[3] = f2bf(w0.w * q);
          v[4] = f2bf(w1.x * q); v[5] = f2bf(w1.y * q);
          v[6] = f2bf(w1.z * q); v[7] = f2bf(w1.w * q);
          *reinterpret_cast<ushort8*>(&Wq[(size_t)row * IK + i * 8]) = v;
        }
      }
    }
    gbar(bar, ep);
  }
}

// ---------------------------------------------------------------------------
extern "C" void kernel_launch(void* const* d_in, const int* in_sizes, int n_in,
                              void* d_out, int out_size, void* d_ws, size_t ws_size,
                              hipStream_t stream) {
  const float* x = (const float*)d_in[0];       // [B,K,I] f32
  const float* W = (const float*)d_in[1];       // [I,C,O,K] f32
  float* out = (float*)d_out;                   // [B,C,O,1] f32

  // choose split count by workspace size (deterministic: ws_size is fixed)
  const size_t fixed = 16 + (size_t)(IDIM * CDIM) * 4 +
                       ((size_t)B * IK + (size_t)IK * B + (size_t)CO * IK +
                        (size_t)CO * B) * 2;
  const int np = (ws_size >= fixed + 32ull * B * CO * 4) ? 32 : 8;

  int* bar       = (int*)d_ws;                               // 16 B
  float* logits  = (float*)((char*)d_ws + 16);               // I*C f32
  float* s_part  = logits + IDIM * CDIM;                     // np*B*CO f32
  unsigned short* xtbT = (unsigned short*)(s_part + (size_t)np * B * CO);
  unsigned short* xtkb = xtbT + (size_t)B * IK;
  unsigned short* Wq   = xtkb + (size_t)IK * B;
  unsigned short* outT = Wq + (size_t)CO * IK;

  hipMemsetAsync(bar, 0, 16, stream);
  if (np == 32)
    caps_all<32><<<NBLK, 256, 0, stream>>>(x, W, out, bar, logits, s_part,
                                           xtbT, xtkb, Wq, outT);
  else
    caps_all<8><<<NBLK, 256, 0, stream>>>(x, W, out, bar, logits, s_part,
                                          xtbT, xtkb, Wq, outT);
}

// Round 10
// 286.955 us; speedup vs baseline: 1.5142x; 1.5142x over previous
//
#include <hip/hip_runtime.h>

#define B 256
#define KDIM 8
#define IDIM 1152
#define CDIM 10
#define CO 160
#define IK 9216        // IDIM*KDIM
#define NBLK 256

typedef __bf16 bf16x8 __attribute__((ext_vector_type(8)));
typedef unsigned short ushort8 __attribute__((ext_vector_type(8)));
typedef float f32x4 __attribute__((ext_vector_type(4)));

__device__ __forceinline__ unsigned short f2bf(float f) {
  unsigned u = __float_as_uint(f);
  unsigned r = u + 0x7fff + ((u >> 16) & 1);   // RNE
  return (unsigned short)(r >> 16);
}

union U8B8 { ushort8 u; bf16x8 h; };
union U8U64 { ushort8 s; bf16x8 h; unsigned long long u[2]; };

// ---- LLC-coherent (agent-scope, cache-bypassing) accessors ----------------
__device__ __forceinline__ void st64_llc(void* p, unsigned long long v) {
  __hip_atomic_store((unsigned long long*)p, v, __ATOMIC_RELAXED,
                     __HIP_MEMORY_SCOPE_AGENT);
}
__device__ __forceinline__ unsigned long long ld64_llc(const void* p) {
  return __hip_atomic_load((unsigned long long*)p, __ATOMIC_RELAXED,
                           __HIP_MEMORY_SCOPE_AGENT);
}
__device__ __forceinline__ void st32_llc(void* p, unsigned v) {
  __hip_atomic_store((unsigned*)p, v, __ATOMIC_RELAXED,
                     __HIP_MEMORY_SCOPE_AGENT);
}
__device__ __forceinline__ float ldf_llc(const float* p) {
  return __hip_atomic_load((float*)p, __ATOMIC_RELAXED,
                           __HIP_MEMORY_SCOPE_AGENT);
}

// Fence-free grid barrier: sc1 traffic needs no cache sweeps. __syncthreads
// drains vmcnt (stores complete at LLC) before thread 0 signals arrival.
// Poll is an RMW (always served at the coherence point).
__device__ __forceinline__ void gbar(int* cnt, int& ep) {
  __syncthreads();
  ep += NBLK;
  if (threadIdx.x == 0) {
    atomicAdd(cnt, 1);
    if (atomicAdd(cnt, 0) < ep) {
      __builtin_amdgcn_s_sleep(2);
      int g = 0;
      while (atomicAdd(cnt, 0) < ep) {
        __builtin_amdgcn_s_sleep(32);            // ~0.85 us between polls
        if (++g > 1000000) break;                // bailout: wrong, not hung
      }
    }
  }
  __syncthreads();
}

// Fenced barrier (after prep only): publishes plain-stored read-only buffers
// (xtbT/xtkb/Wq0/logits). Exactly one release + one acquire fence per block.
__device__ __forceinline__ void gbar_fence(int* cnt, int& ep) {
  __syncthreads();
  ep += NBLK;
  if (threadIdx.x == 0) {
    __threadfence();                             // writeback XCD L2 -> LLC
    atomicAdd(cnt, 1);
    if (atomicAdd(cnt, 0) < ep) {
      __builtin_amdgcn_s_sleep(2);
      int g = 0;
      while (atomicAdd(cnt, 0) < ep) {
        __builtin_amdgcn_s_sleep(32);
        if (++g > 1000000) break;
      }
    }
    __threadfence();                             // invalidate stale L1/L2
  }
  __syncthreads();
}

// ---------------------------------------------------------------------------
// Single persistent kernel, 256 blocks x 256 threads.
// P (plain stores, fenced barrier) ->
// iter: S (MFMA split-K, Wq sc1-in, s_part sc1-out) -> SQ (s_part sc1-in,
//       outT sc1-out / final f32 out) -> AGR (outT sc1-in, logits atomic) ->
//       Q (logits sc1-in, Wq sc1-out)
// ---------------------------------------------------------------------------
template <int NP>
__global__ void __launch_bounds__(256)
caps_all(const float* __restrict__ x, const float* __restrict__ W,
         float* __restrict__ out, int* __restrict__ bar,
         float* __restrict__ logits, float* __restrict__ s_part,
         unsigned short* __restrict__ xtbT, unsigned short* __restrict__ xtkb,
         unsigned short* __restrict__ Wq, unsigned short* __restrict__ outT) {
  __shared__ __align__(16) unsigned char smem[41280];
  const int gid = blockIdx.x;
  const int t = threadIdx.x;
  const int w4 = t >> 6, l = t & 63;
  const int lr = l & 15, lq = l >> 4;
  const int gwid = gid * 4 + w4;
  int ep = 0;

  // ================= Phase P: prep (plain stores) =================
  for (int job = gid; job < 360; job += NBLK) {
    if (job < 288) {
      float* tf = (float*)smem;            // tile[k][bb][ii]: k*1056+bb*33+ii
      const int i0 = (job % 36) * 32;
      const int b0 = (job / 36) * 32;
      const int tx = t & 31, ty = t >> 5;
#pragma unroll
      for (int r = 0; r < 4; ++r) {
        int b = b0 + ty + r * 8;
#pragma unroll
        for (int k = 0; k < 8; ++k)
          tf[k * 1056 + (ty + r * 8) * 33 + tx] =
              x[((size_t)b * KDIM + k) * IDIM + i0 + tx];
      }
      __syncthreads();
#pragma unroll
      for (int r = 0; r < 4; ++r) {
        int idx = r * 256 + t;
        int bb = idx >> 5, ii = idx & 31;
        ushort8 v;
#pragma unroll
        for (int k = 0; k < 8; ++k) v[k] = f2bf(tf[k * 1056 + bb * 33 + ii]);
        *reinterpret_cast<ushort8*>(&xtbT[(size_t)(b0 + bb) * IK + (i0 + ii) * 8]) = v;
      }
#pragma unroll
      for (int ii = 0; ii < 32; ++ii)
        xtkb[((size_t)(i0 + ii) * 8 + ty) * B + b0 + tx] =
            f2bf(tf[ty * 1056 + tx * 33 + ii]);
    } else {
      unsigned short* wt = (unsigned short*)smem;  // wt[ii][j], stride 1288
      const int bz = job - 288;
      const int i0 = bz * 16;
      const float sc = 1.f / (float)IDIM;
#pragma unroll
      for (int ii = 0; ii < 16; ++ii) {
        const float* src = &W[(size_t)(i0 + ii) * 1280];
#pragma unroll
        for (int p = 0; p < 5; ++p) {
          int j = p * 256 + t;
          wt[ii * 1288 + j] = f2bf(src[j] * sc);
        }
      }
      __syncthreads();
#pragma unroll
      for (int p = 0; p < 10; ++p) {
        int idx = p * 256 + t;
        int co = idx >> 4, ii = idx & 15;
        ushort8 v = *reinterpret_cast<const ushort8*>(&wt[ii * 1288 + co * 8]);
        *reinterpret_cast<ushort8*>(&Wq[(size_t)co * IK + (i0 + ii) * 8]) = v;
      }
    }
    __syncthreads();
  }
  if (gid < 45) logits[gid * 256 + t] = 0.f;
  gbar_fence(bar, ep);

  for (int it = 0; it < 3; ++it) {
    // ================= Phase S: split-K MFMA s-GEMM =================
    {
      constexpr int KSPAN = IK / NP;
      constexpr int CHUNKS = KSPAN / 32;
      for (int job = gwid; job < 160 * NP; job += 1024) {
        const int bt = job & 15;
        const int cc = (job >> 4) % 10;
        const int g = job / 160;
        const unsigned short* Ap = &Wq[(size_t)(cc * 16 + lr) * IK + g * KSPAN + lq * 8];
        const unsigned short* Bp = &xtbT[(size_t)(bt * 16 + lr) * IK + g * KSPAN + lq * 8];
        f32x4 acc = (f32x4){0.f, 0.f, 0.f, 0.f};
#pragma unroll 3
        for (int t9 = 0; t9 < CHUNKS; ++t9) {
          U8U64 a;
          a.u[0] = ld64_llc(Ap + t9 * 32);
          a.u[1] = ld64_llc(Ap + t9 * 32 + 4);
          U8B8 bb;
          bb.u = *reinterpret_cast<const ushort8*>(Bp + t9 * 32);  // cached
          acc = __builtin_amdgcn_mfma_f32_16x16x32_bf16(a.h, bb.h, acc, 0, 0, 0);
        }
        union { f32x4 f; unsigned long long u[2]; } cv;
        cv.f = acc;
        float* dp = &s_part[((size_t)g * B + bt * 16 + lr) * CO + cc * 16 + lq * 4];
        st64_llc(dp, cv.u[0]);
        st64_llc(dp + 2, cv.u[1]);
      }
    }
    gbar(bar, ep);

    // ================= Phase SQ: reduce + squash (blocks 0..127, 2 b each) ==
    {
      float* sq = (float*)smem;      // [2][160] v^2
      float* fo = sq + 320;          // [2][16]
      if (gid < 128) {
        const int b0 = gid * 2;
        float r2[2] = {0.f, 0.f};
        if (t < CO) {
#pragma unroll
          for (int bi = 0; bi < 2; ++bi) {
            float vv = 0.f;
#pragma unroll 4
            for (int g = 0; g < NP; ++g)
              vv += ldf_llc(&s_part[((size_t)g * B + b0 + bi) * CO + t]);
            sq[bi * 160 + t] = vv * vv;
            r2[bi] = vv;
          }
        }
        __syncthreads();
        if (t < 32) {
          int bi = t >> 4, o = t & 15;
          float ns = 0.f;
#pragma unroll
          for (int c = 0; c < CDIM; ++c) ns += sq[bi * 160 + c * 16 + o];
          fo[bi * 16 + o] = (ns / (1.f + ns)) / (sqrtf(ns) + 1e-10f);
        }
        __syncthreads();
        if (t < CO) {
          float v0 = r2[0] * fo[t & 15];
          float v1 = r2[1] * fo[16 + (t & 15)];
          if (it == 2) {
            out[(size_t)b0 * CO + t] = v0;
            out[(size_t)(b0 + 1) * CO + t] = v1;
          } else {
            unsigned u = (unsigned)f2bf(v0) | ((unsigned)f2bf(v1) << 16);
            st32_llc(&outT[(size_t)t * B + b0], u);
          }
        }
      }
    }
    if (it == 2) break;
    gbar(bar, ep);

    // ================= Phase AGR: MFMA y-GEMM + W-contract =================
    {
      float* yl = (float*)smem;      // [64][161]
      for (int job = gid; job < 576; job += NBLK) {
        const int bx = job % 144, bh = job / 144;
        __syncthreads();             // protect yl reuse across jobs
        f32x4 acc[10];
#pragma unroll
        for (int nt = 0; nt < 10; ++nt) acc[nt] = (f32x4){0.f, 0.f, 0.f, 0.f};
        const unsigned short* Ap =
            &xtkb[(size_t)(bx * 64 + w4 * 16 + lr) * B + bh * 64 + lq * 8];
        const unsigned short* Bp = &outT[(size_t)lr * B + bh * 64 + lq * 8];
#pragma unroll
        for (int kc = 0; kc < 2; ++kc) {
          U8B8 a;
          a.u = *reinterpret_cast<const ushort8*>(Ap + kc * 32);  // cached
#pragma unroll
          for (int nt = 0; nt < 10; ++nt) {
            U8U64 bv;
            bv.u[0] = ld64_llc(Bp + (size_t)nt * 16 * B + kc * 32);
            bv.u[1] = ld64_llc(Bp + (size_t)nt * 16 * B + kc * 32 + 4);
            acc[nt] = __builtin_amdgcn_mfma_f32_16x16x32_bf16(a.h, bv.h, acc[nt], 0, 0, 0);
          }
        }
#pragma unroll
        for (int nt = 0; nt < 10; ++nt)
#pragma unroll
          for (int j = 0; j < 4; ++j)
            yl[(w4 * 16 + lq * 4 + j) * 161 + nt * 16 + lr] = acc[nt][j];
        __syncthreads();
        if (t < 160) {
          const int ii = t / 20, rem = t % 20, ccl = rem >> 1, oh = rem & 1;
          const float* Wp = &W[((size_t)(bx * 8 + ii) * CDIM + ccl) * 128 + oh * 64];
          float sum = 0.f;
#pragma unroll
          for (int o = 0; o < 8; ++o) {
            float4 w0 = *(const float4*)(&Wp[o * 8]);
            float4 w1 = *(const float4*)(&Wp[o * 8 + 4]);
            int co = ccl * 16 + oh * 8 + o;
            sum += w0.x * yl[(ii * 8 + 0) * 161 + co] + w0.y * yl[(ii * 8 + 1) * 161 + co]
                 + w0.z * yl[(ii * 8 + 2) * 161 + co] + w0.w * yl[(ii * 8 + 3) * 161 + co]
                 + w1.x * yl[(ii * 8 + 4) * 161 + co] + w1.y * yl[(ii * 8 + 5) * 161 + co]
                 + w1.z * yl[(ii * 8 + 6) * 161 + co] + w1.w * yl[(ii * 8 + 7) * 161 + co];
          }
          sum += __shfl_xor(sum, 1);
          if (oh == 0)
            atomicAdd(&logits[(bx * 8 + ii) * CDIM + ccl], sum * (1.f / (float)B));
        }
      }
    }
    gbar(bar, ep);

    // ================= Phase Q: softmax + Wq = bf16(W*q) =================
    if (gid < 40) {
      const int c = gid >> 2;
      const int o0 = (gid & 3) * 4;
      float* cls = (float*)smem;     // [1152]
      float* red4 = cls + IDIM;      // [4]
      float m = -1e30f;
      for (int i = t; i < IDIM; i += 256) {
        float v = ldf_llc(&logits[i * CDIM + c]);
        cls[i] = v;
        m = fmaxf(m, v);
      }
#pragma unroll
      for (int off = 32; off; off >>= 1) m = fmaxf(m, __shfl_xor(m, off));
      if ((t & 63) == 0) red4[t >> 6] = m;
      __syncthreads();
      m = fmaxf(fmaxf(red4[0], red4[1]), fmaxf(red4[2], red4[3]));
      __syncthreads();
      float ps = 0.f;
      for (int i = t; i < IDIM; i += 256) {
        float e = expf(cls[i] - m);
        cls[i] = e;
        ps += e;
      }
#pragma unroll
      for (int off = 32; off; off >>= 1) ps += __shfl_xor(ps, off);
      if ((t & 63) == 0) red4[t >> 6] = ps;
      __syncthreads();
      const float rinv = 1.f / (red4[0] + red4[1] + red4[2] + red4[3]);
#pragma unroll
      for (int r = 0; r < 4; ++r) {
        int row = c * 16 + o0 + r;
        for (int i = t; i < IDIM; i += 256) {
          const float* src = &W[((size_t)i * CDIM + c) * 128 + (o0 + r) * 8];
          float q = cls[i] * rinv;
          float4 w0 = *(const float4*)src;
          float4 w1 = *(const float4*)(src + 4);
          U8U64 v;
          v.s[0] = f2bf(w0.x * q); v.s[1] = f2bf(w0.y * q);
          v.s[2] = f2bf(w0.z * q); v.s[3] = f2bf(w0.w * q);
          v.s[4] = f2bf(w1.x * q); v.s[5] = f2bf(w1.y * q);
          v.s[6] = f2bf(w1.z * q); v.s[7] = f2bf(w1.w * q);
          unsigned short* dp = &Wq[(size_t)row * IK + i * 8];
          st64_llc(dp, v.u[0]);
          st64_llc(dp + 4, v.u[1]);
        }
      }
    }
    gbar(bar, ep);
  }
}

// ---------------------------------------------------------------------------
extern "C" void kernel_launch(void* const* d_in, const int* in_sizes, int n_in,
                              void* d_out, int out_size, void* d_ws, size_t ws_size,
                              hipStream_t stream) {
  const float* x = (const float*)d_in[0];       // [B,K,I] f32
  const float* W = (const float*)d_in[1];       // [I,C,O,K] f32
  float* out = (float*)d_out;                   // [B,C,O,1] f32

  const size_t fixed = 16 + (size_t)(IDIM * CDIM) * 4 +
                       ((size_t)B * IK + (size_t)IK * B + (size_t)CO * IK +
                        (size_t)CO * B) * 2;
  const int np = (ws_size >= fixed + 32ull * B * CO * 4) ? 32 : 8;

  int* bar       = (int*)d_ws;                               // 16 B
  float* logits  = (float*)((char*)d_ws + 16);               // I*C f32
  float* s_part  = logits + IDIM * CDIM;                     // np*B*CO f32
  unsigned short* xtbT = (unsigned short*)(s_part + (size_t)np * B * CO);
  unsigned short* xtkb = xtbT + (size_t)B * IK;
  unsigned short* Wq   = xtkb + (size_t)IK * B;
  unsigned short* outT = Wq + (size_t)CO * IK;

  hipMemsetAsync(bar, 0, 16, stream);
  if (np == 32)
    caps_all<32><<<NBLK, 256, 0, stream>>>(x, W, out, bar, logits, s_part,
                                           xtbT, xtkb, Wq, outT);
  else
    caps_all<8><<<NBLK, 256, 0, stream>>>(x, W, out, bar, logits, s_part,
                                          xtbT, xtkb, Wq, outT);
}

// Round 11
// 226.663 us; speedup vs baseline: 1.9170x; 1.2660x over previous
//
#include <hip/hip_runtime.h>

#define B 256
#define KDIM 8
#define IDIM 1152
#define CDIM 10
#define CO 160
#define IK 9216        // IDIM*KDIM
#define NBLK 256
#define NTHR 512

typedef __bf16 bf16x8 __attribute__((ext_vector_type(8)));
typedef unsigned short ushort8 __attribute__((ext_vector_type(8)));
typedef float f32x4 __attribute__((ext_vector_type(4)));

__device__ __forceinline__ unsigned short f2bf(float f) {
  unsigned u = __float_as_uint(f);
  unsigned r = u + 0x7fff + ((u >> 16) & 1);   // RNE
  return (unsigned short)(r >> 16);
}

union U8B8 { ushort8 u; bf16x8 h; };
union U8U64 { ushort8 s; bf16x8 h; unsigned long long u[2]; };

// ---- LLC-coherent (agent-scope, cache-bypassing) accessors ----------------
__device__ __forceinline__ void st64_llc(void* p, unsigned long long v) {
  __hip_atomic_store((unsigned long long*)p, v, __ATOMIC_RELAXED,
                     __HIP_MEMORY_SCOPE_AGENT);
}
__device__ __forceinline__ unsigned long long ld64_llc(const void* p) {
  return __hip_atomic_load((unsigned long long*)p, __ATOMIC_RELAXED,
                           __HIP_MEMORY_SCOPE_AGENT);
}
__device__ __forceinline__ void st32_llc(void* p, unsigned v) {
  __hip_atomic_store((unsigned*)p, v, __ATOMIC_RELAXED,
                     __HIP_MEMORY_SCOPE_AGENT);
}
__device__ __forceinline__ float ldf_llc(const float* p) {
  return __hip_atomic_load((float*)p, __ATOMIC_RELAXED,
                           __HIP_MEMORY_SCOPE_AGENT);
}

// Fence-free grid barrier (sc1 data needs no cache sweeps).
__device__ __forceinline__ void gbar(int* cnt, int& ep) {
  __syncthreads();
  ep += NBLK;
  if (threadIdx.x == 0) {
    atomicAdd(cnt, 1);
    int g = 0;
    while (atomicAdd(cnt, 0) < ep) {
      __builtin_amdgcn_s_sleep(8);
      if (++g > 4000000) break;                  // bailout: wrong, not hung
    }
  }
  __syncthreads();
}

// Fenced barrier (after prep only): publishes plain-stored xtbT/xtkb/logits.
__device__ __forceinline__ void gbar_fence(int* cnt, int& ep) {
  __syncthreads();
  ep += NBLK;
  if (threadIdx.x == 0) {
    __threadfence();
    atomicAdd(cnt, 1);
    int g = 0;
    while (atomicAdd(cnt, 0) < ep) {
      __builtin_amdgcn_s_sleep(8);
      if (++g > 4000000) break;
    }
    __threadfence();
  }
  __syncthreads();
}

// ---------------------------------------------------------------------------
// Persistent kernel: 256 blocks x 512 threads (8 waves; 2/SIMD; 1 block/CU).
// P (x->xtbT,xtkb bf16 plain; qT=1/I sc1; logits=0 plain) -> fenced bar
// iter: S   s[o,b] += bf16(W*q)x(xtbT) MFMA split-K -> s_part (sc1)
//       SQ  reduce+squash -> outT bf16 (sc1) / final f32 out
//       AGR y=xtkb*outT^T MFMA -> W-contract -> atomicAdd logits
//       Q   softmax(logits) -> qT (sc1)
// ---------------------------------------------------------------------------
template <int NP>
__global__ void __launch_bounds__(NTHR)
caps_all(const float* __restrict__ x, const float* __restrict__ W,
         float* __restrict__ out, int* __restrict__ bar,
         float* __restrict__ logits, float* __restrict__ qT,
         float* __restrict__ s_part, unsigned short* __restrict__ xtbT,
         unsigned short* __restrict__ xtkb, unsigned short* __restrict__ outT) {
  __shared__ __align__(16) unsigned char smem[82944];
  const int gid = blockIdx.x;
  const int t = threadIdx.x;
  const int w8 = t >> 6, l = t & 63;
  const int lr = l & 15, lq = l >> 4;
  const int gwid = gid * 8 + w8;           // 0..2047
  int ep = 0;

  // ================= Phase P: prep =================
  for (int job = gid; job < 288; job += NBLK) {
    float* tf = (float*)smem;              // tile[k][bb][ii]: k*1056+bb*33+ii
    const int i0 = (job % 36) * 32;
    const int b0 = (job / 36) * 32;
    const int tx = t & 31, ty = t >> 5;    // ty 0..15
#pragma unroll
    for (int r = 0; r < 2; ++r) {
      int b = b0 + ty + r * 16;
#pragma unroll
      for (int k = 0; k < 8; ++k)
        tf[k * 1056 + (ty + r * 16) * 33 + tx] =
            x[((size_t)b * KDIM + k) * IDIM + i0 + tx];
    }
    __syncthreads();
    // xtbT[b][i*8+k]
#pragma unroll
    for (int r = 0; r < 2; ++r) {
      int idx = r * 512 + t;
      int bb = idx >> 5, ii = idx & 31;
      ushort8 v;
#pragma unroll
      for (int k = 0; k < 8; ++k) v[k] = f2bf(tf[k * 1056 + bb * 33 + ii]);
      *reinterpret_cast<ushort8*>(&xtbT[(size_t)(b0 + bb) * IK + (i0 + ii) * 8]) = v;
    }
    // xtkb[(i*8+k)][b]
    {
      const int k = ty & 7, half = ty >> 3;
#pragma unroll
      for (int r = 0; r < 16; ++r) {
        int ii = half * 16 + r;
        xtkb[((size_t)(i0 + ii) * 8 + k) * B + b0 + tx] =
            f2bf(tf[k * 1056 + tx * 33 + ii]);
      }
    }
    __syncthreads();
  }
  if (gid < 10)
    for (int i = t; i < IDIM; i += NTHR)
      st32_llc(&qT[gid * IDIM + i], __float_as_uint(1.f / (float)IDIM));
  if (gid < 23) {
    int idx = gid * NTHR + t;
    if (idx < IDIM * CDIM) logits[idx] = 0.f;
  }
  gbar_fence(bar, ep);

  for (int it = 0; it < 3; ++it) {
    // ================= Phase S: split-K MFMA s-GEMM =================
    {
      constexpr int KSPAN = IK / NP;       // 288 at NP=32
      constexpr int CHUNKS = KSPAN / 32;   // 9
      constexpr int ISPAN = KSPAN / 8;     // 36 i's per split
      for (int job = gwid; job < 160 * NP; job += 2048) {
        const int bt = job & 15;
        const int cc = (job >> 4) % 10;
        const int g = job / 160;
        const unsigned short* Bp =
            &xtbT[(size_t)(bt * 16 + lr) * IK + g * KSPAN + lq * 8];
        const float* qp = &qT[cc * IDIM + g * ISPAN + lq];
        f32x4 acc = (f32x4){0.f, 0.f, 0.f, 0.f};
#pragma unroll 3
        for (int t9 = 0; t9 < CHUNKS; ++t9) {
          const int i = g * ISPAN + t9 * 4 + lq;
          const float* wsrc = &W[((size_t)i * CDIM + cc) * 128 + lr * 8];
          float4 w0 = *(const float4*)wsrc;
          float4 w1 = *(const float4*)(wsrc + 4);
          float qv = ldf_llc(qp + t9 * 4);
          U8B8 a;
          a.u[0] = f2bf(w0.x * qv); a.u[1] = f2bf(w0.y * qv);
          a.u[2] = f2bf(w0.z * qv); a.u[3] = f2bf(w0.w * qv);
          a.u[4] = f2bf(w1.x * qv); a.u[5] = f2bf(w1.y * qv);
          a.u[6] = f2bf(w1.z * qv); a.u[7] = f2bf(w1.w * qv);
          U8B8 bb;
          bb.u = *reinterpret_cast<const ushort8*>(Bp + t9 * 32);  // cached
          acc = __builtin_amdgcn_mfma_f32_16x16x32_bf16(a.h, bb.h, acc, 0, 0, 0);
        }
        union { f32x4 f; unsigned long long u[2]; } cv;
        cv.f = acc;
        float* dp = &s_part[((size_t)g * B + bt * 16 + lr) * CO + cc * 16 + lq * 4];
        st64_llc(dp, cv.u[0]);
        st64_llc(dp + 2, cv.u[1]);
      }
    }
    gbar(bar, ep);

    // ================= Phase SQ: reduce + squash (2 b per block) ===========
    {
      float* sq = (float*)smem;      // [2][160], then reused for squashed vals
      float* fo = sq + 320;          // [2][16]
      if (gid < 128) {
        const int b0 = gid * 2;
        const int bi = t / 160, tt = t % 160;
        float vv = 0.f;
        if (t < 320) {
#pragma unroll 4
          for (int g = 0; g < NP; ++g)
            vv += ldf_llc(&s_part[((size_t)g * B + b0 + bi) * CO + tt]);
          sq[bi * 160 + tt] = vv * vv;
        }
        __syncthreads();
        if (t < 32) {
          int bj = t >> 4, o = t & 15;
          float ns = 0.f;
#pragma unroll
          for (int c = 0; c < CDIM; ++c) ns += sq[bj * 160 + c * 16 + o];
          fo[bj * 16 + o] = (ns / (1.f + ns)) / (sqrtf(ns) + 1e-10f);
        }
        __syncthreads();
        if (t < 320) {
          float v = vv * fo[bi * 16 + (tt & 15)];
          if (it == 2) out[(size_t)(b0 + bi) * CO + tt] = v;
          else         sq[bi * 160 + tt] = v;
        }
        if (it != 2) {
          __syncthreads();
          if (t < 160) {
            unsigned u = (unsigned)f2bf(sq[t]) | ((unsigned)f2bf(sq[160 + t]) << 16);
            st32_llc(&outT[(size_t)t * B + b0], u);
          }
        }
      }
    }
    if (it == 2) break;
    gbar(bar, ep);

    // ================= Phase AGR: MFMA y-GEMM + W-contract =================
    {
      float* yl = (float*)smem;      // [128][161] f32 = 82.4 KB
      for (int job = gid; job < 288; job += NBLK) {
        const int bx = job % 72, bh = job / 72;
        __syncthreads();             // protect yl reuse across jobs
        f32x4 acc[10];
#pragma unroll
        for (int nt = 0; nt < 10; ++nt) acc[nt] = (f32x4){0.f, 0.f, 0.f, 0.f};
        const unsigned short* Ap =
            &xtkb[(size_t)(bx * 128 + w8 * 16 + lr) * B + bh * 64 + lq * 8];
        const unsigned short* Bp = &outT[(size_t)lr * B + bh * 64 + lq * 8];
#pragma unroll
        for (int kc = 0; kc < 2; ++kc) {
          U8B8 a;
          a.u = *reinterpret_cast<const ushort8*>(Ap + kc * 32);  // cached
#pragma unroll
          for (int nt = 0; nt < 10; ++nt) {
            U8U64 bv;
            bv.u[0] = ld64_llc(Bp + (size_t)nt * 16 * B + kc * 32);
            bv.u[1] = ld64_llc(Bp + (size_t)nt * 16 * B + kc * 32 + 4);
            acc[nt] = __builtin_amdgcn_mfma_f32_16x16x32_bf16(a.h, bv.h, acc[nt], 0, 0, 0);
          }
        }
#pragma unroll
        for (int nt = 0; nt < 10; ++nt)
#pragma unroll
          for (int j = 0; j < 4; ++j)
            yl[(w8 * 16 + lq * 4 + j) * 161 + nt * 16 + lr] = acc[nt][j];
        __syncthreads();
        if (t < 320) {
          const int ii = t / 20, rem = t % 20, ccl = rem >> 1, oh = rem & 1;
          const float* Wp = &W[((size_t)(bx * 16 + ii) * CDIM + ccl) * 128 + oh * 64];
          float sum = 0.f;
#pragma unroll
          for (int o = 0; o < 8; ++o) {
            float4 w0 = *(const float4*)(&Wp[o * 8]);
            float4 w1 = *(const float4*)(&Wp[o * 8 + 4]);
            int co = ccl * 16 + oh * 8 + o;
            sum += w0.x * yl[(ii * 8 + 0) * 161 + co] + w0.y * yl[(ii * 8 + 1) * 161 + co]
                 + w0.z * yl[(ii * 8 + 2) * 161 + co] + w0.w * yl[(ii * 8 + 3) * 161 + co]
                 + w1.x * yl[(ii * 8 + 4) * 161 + co] + w1.y * yl[(ii * 8 + 5) * 161 + co]
                 + w1.z * yl[(ii * 8 + 6) * 161 + co] + w1.w * yl[(ii * 8 + 7) * 161 + co];
          }
          sum += __shfl_xor(sum, 1);
          if (oh == 0)
            atomicAdd(&logits[(bx * 16 + ii) * CDIM + ccl], sum * (1.f / (float)B));
        }
      }
    }
    gbar(bar, ep);

    // ================= Phase Q: softmax -> qT =================
    if (gid < 10) {
      const int c = gid;
      float* cls = (float*)smem;     // [1152]
      float* red8 = cls + IDIM;      // [8]
      float m = -1e30f;
      for (int i = t; i < IDIM; i += NTHR) {
        float v = ldf_llc(&logits[i * CDIM + c]);
        cls[i] = v;
        m = fmaxf(m, v);
      }
#pragma unroll
      for (int off = 32; off; off >>= 1) m = fmaxf(m, __shfl_xor(m, off));
      if ((t & 63) == 0) red8[t >> 6] = m;
      __syncthreads();
#pragma unroll
      for (int r = 0; r < 8; ++r) m = fmaxf(m, red8[r]);
      __syncthreads();
      float ps = 0.f;
      for (int i = t; i < IDIM; i += NTHR) {
        float e = expf(cls[i] - m);
        cls[i] = e;
        ps += e;
      }
#pragma unroll
      for (int off = 32; off; off >>= 1) ps += __shfl_xor(ps, off);
      if ((t & 63) == 0) red8[t >> 6] = ps;
      __syncthreads();
      float tot = 0.f;
#pragma unroll
      for (int r = 0; r < 8; ++r) tot += red8[r];
      const float rinv = 1.f / tot;
      for (int i = t; i < IDIM; i += NTHR)
        st32_llc(&qT[c * IDIM + i], __float_as_uint(cls[i] * rinv));
    }
    gbar(bar, ep);
  }
}

// ---------------------------------------------------------------------------
extern "C" void kernel_launch(void* const* d_in, const int* in_sizes, int n_in,
                              void* d_out, int out_size, void* d_ws, size_t ws_size,
                              hipStream_t stream) {
  const float* x = (const float*)d_in[0];       // [B,K,I] f32
  const float* W = (const float*)d_in[1];       // [I,C,O,K] f32
  float* out = (float*)d_out;                   // [B,C,O,1] f32

  const size_t fixed = 16 + (size_t)(IDIM * CDIM) * 8 +
                       ((size_t)B * IK + (size_t)IK * B + (size_t)CO * B) * 2;
  const int np = (ws_size >= fixed + 32ull * B * CO * 4) ? 32 : 8;

  int* bar       = (int*)d_ws;                               // 16 B
  float* logits  = (float*)((char*)d_ws + 16);               // I*C f32
  float* qT      = logits + IDIM * CDIM;                     // C*I f32
  float* s_part  = qT + IDIM * CDIM;                         // np*B*CO f32
  unsigned short* xtbT = (unsigned short*)(s_part + (size_t)np * B * CO);
  unsigned short* xtkb = xtbT + (size_t)B * IK;
  unsigned short* outT = xtkb + (size_t)IK * B;

  hipMemsetAsync(bar, 0, 16, stream);
  if (np == 32)
    caps_all<32><<<NBLK, NTHR, 0, stream>>>(x, W, out, bar, logits, qT,
                                            s_part, xtbT, xtkb, outT);
  else
    caps_all<8><<<NBLK, NTHR, 0, stream>>>(x, W, out, bar, logits, qT,
                                           s_part, xtbT, xtkb, outT);
}